// Round 9
// baseline (591.435 us; speedup 1.0000x reference)
//
#include <hip/hip_runtime.h>
#include <math.h>

// Problem constants (match reference setup_inputs()).
#define F_IN    384
#define N1      128
#define N2      96
#define N3      2
#define NEXP    4
#define BM      64            // tokens per block tile

typedef __attribute__((ext_vector_type(8))) short           bf16x8;   // MFMA A/B frag
typedef __attribute__((ext_vector_type(4))) float           f32x4;    // MFMA C/D frag
typedef __attribute__((ext_vector_type(8))) unsigned short  us8;

// fp32 -> bf16 RNE (values are finite; no NaN handling needed)
__device__ __forceinline__ unsigned short f2bf(float f) {
  unsigned int u = __float_as_uint(f);
  return (unsigned short)((u + 0x7FFFu + ((u >> 16) & 1u)) >> 16);
}

// ws layout:
//   ints [0..4) counts, [4..8) offsets, [8..12) cursors, [16..16+T) token list
//   byte 64+4T (64B-aligned): Wt1 [4][128][384] bf16 (393216 B)
//   then:                     Wt2 [4][96][128]  bf16 ( 98304 B)
// Total ws requirement ~1.02 MB.

// ---------------------------------------------------------------------------
// Pass 1: histogram + elements passthrough (as float — confirmed PASS r7).
// ---------------------------------------------------------------------------
__global__ __launch_bounds__(256) void hist_kernel(
    const int* __restrict__ el, float* __restrict__ out_el,
    int* __restrict__ counts, int T) {
  int t = blockIdx.x * blockDim.x + threadIdx.x;
  if (t >= T) return;
  int e = el[t];
  out_el[t] = (float)e;
#pragma unroll
  for (int v = 0; v < NEXP; ++v) {
    unsigned long long m = __ballot(e == v);
    if (e == v) {
      int lane = threadIdx.x & 63;
      int leader = __ffsll(m) - 1;
      if (lane == leader) atomicAdd(&counts[v], __popcll(m));
    }
  }
}

__global__ void scan_kernel(int* __restrict__ ws) {
  if (threadIdx.x == 0) {
    int o = 0;
#pragma unroll
    for (int e = 0; e < NEXP; ++e) {
      ws[4 + e] = o;
      ws[8 + e] = o;
      o += ws[e];
    }
  }
}

__global__ __launch_bounds__(256) void scatter_kernel(
    const int* __restrict__ el, int* __restrict__ cursors,
    int* __restrict__ list, int T) {
  int t = blockIdx.x * blockDim.x + threadIdx.x;
  if (t >= T) return;
  int e = el[t];
  int lane = threadIdx.x & 63;
  unsigned long long lt = (lane == 0) ? 0ull : ((~0ull) >> (64 - lane));
#pragma unroll
  for (int v = 0; v < NEXP; ++v) {
    unsigned long long m = __ballot(e == v);
    if (e == v) {
      int leader = __ffsll(m) - 1;
      int prefix = __popcll(m & lt);
      int base = 0;
      if (lane == leader) base = atomicAdd(&cursors[v], __popcll(m));
      base = __shfl(base, leader, 64);
      list[base + prefix] = t;
    }
  }
}

// ---------------------------------------------------------------------------
// Weight prep: W1 [e][k][n] f32 -> Wt1 [e][n][k] bf16;  W2 likewise.
// ---------------------------------------------------------------------------
__global__ __launch_bounds__(256) void prep_weights(
    const float* __restrict__ W1, const float* __restrict__ W2,
    unsigned short* __restrict__ Wt1, unsigned short* __restrict__ Wt2) {
  int i = blockIdx.x * 256 + threadIdx.x;
  const int n1 = NEXP * N1 * F_IN;           // 196608
  if (i < n1) {
    int e = i / (N1 * F_IN), r = i % (N1 * F_IN);
    int n = r / F_IN, k = r % F_IN;
    Wt1[i] = f2bf(W1[(e * F_IN + k) * N1 + n]);
  } else {
    int j = i - n1;
    if (j < NEXP * N2 * N1) {
      int e = j / (N2 * N1), r = j % (N2 * N1);
      int n = r / N1, k = r % N1;
      Wt2[j] = f2bf(W2[(e * N1 + k) * N2 + n]);
    }
  }
}

// ---------------------------------------------------------------------------
// Fused 3-layer MLP. Barrier-free MFMA main loops: A and B fragments are
// fetched DIRECTLY from global (X rows are lane-unique per wave; bf16
// weights are L2-hot and shared by all ~512 blocks of an expert), so the
// stage->barrier->mfma->barrier lockstep of r8 (16 barrier pairs/block,
// each a full vmcnt(0) drain) collapses to 4 barriers total (H and H2
// LDS handoffs).
// Wave w owns output rows w*16..w*16+15 for ALL layers.
// Fragment conventions (mfma_f32_16x16x32_bf16, r8-PASS-verified):
//   A[m][k]: m=lane&15, k=(lane>>4)*8+j   B[k][n]: n=lane&15, k=(lane>>4)*8+j
//   C/D[r][c]: c=lane&15, r=(lane>>4)*4+reg
// LDS (ushort units): HU[64][136] @0 (17408B) ; H2f[64][100] f32 @0
// (25600B, overlaps HU after barrier) ; W3s 192 f32 @12800 (768B).
// ---------------------------------------------------------------------------
__global__ __launch_bounds__(256) void moe_mlp_mfma(
    const float* __restrict__ X,
    const float* __restrict__ b1, const float* __restrict__ b2,
    const float* __restrict__ W3, const float* __restrict__ b3,
    const int* __restrict__ ws_i,
    const unsigned short* __restrict__ Wt1,
    const unsigned short* __restrict__ Wt2,
    float* __restrict__ Y, int T) {
  const int e = blockIdx.y;
  const int cnt = ws_i[e];
  const int m0 = blockIdx.x * BM;
  if (m0 >= cnt) return;
  const int* list = ws_i + 16 + ws_i[4 + e];

  __shared__ __align__(16) unsigned short arena[13184];
  __shared__ int toks[BM];
  unsigned short* HU  = arena;              // [64][136] bf16
  float* H2f = (float*)arena;               // [64][100] f32 (overlaps HU)
  float* W3s = (float*)(arena + 12800);     // 192 f32

  const int tid  = threadIdx.x;
  const int lane = tid & 63;
  const int w    = tid >> 6;      // wave 0..3; owns rows w*16..
  const int ln15 = lane & 15;
  const int g    = lane >> 4;     // 0..3

  if (tid < BM) {
    int gi = m0 + tid;
    toks[tid] = (gi < cnt) ? list[gi] : -1;
  }
  __syncthreads();

  const int myrow = w * 16 + ln15;
  const int mytok = toks[myrow];            // lane-unique X row (garbage rows
  const int saferow = mytok < 0 ? 0 : mytok;//  never escape: Y write guarded)
  const float* xrow = X + (size_t)saferow * F_IN + g * 8;

  // ---------------- Layer 1: [64x384]@[384x128], no barriers ---------------
  f32x4 acc[8];
#pragma unroll
  for (int j = 0; j < 8; ++j) acc[j] = (f32x4){0.f, 0.f, 0.f, 0.f};

  const unsigned short* Wt1e =
      Wt1 + (size_t)e * (N1 * F_IN) + (size_t)ln15 * F_IN + g * 8;
#pragma unroll
  for (int ks = 0; ks < F_IN / 32; ++ks) {
    const int k0 = ks * 32;
    float4 lo = *(const float4*)&xrow[k0];
    float4 hi = *(const float4*)&xrow[k0 + 4];
    us8 a8;
    a8[0] = f2bf(lo.x); a8[1] = f2bf(lo.y); a8[2] = f2bf(lo.z); a8[3] = f2bf(lo.w);
    a8[4] = f2bf(hi.x); a8[5] = f2bf(hi.y); a8[6] = f2bf(hi.z); a8[7] = f2bf(hi.w);
    bf16x8 af = *(bf16x8*)&a8;
#pragma unroll
    for (int ct = 0; ct < 8; ++ct) {
      bf16x8 bf = *(const bf16x8*)&Wt1e[ct * 16 * F_IN + k0];
      acc[ct] = __builtin_amdgcn_mfma_f32_16x16x32_bf16(af, bf, acc[ct], 0, 0, 0);
    }
  }

  // bias + celu (f32), write H bf16
#pragma unroll
  for (int ct = 0; ct < 8; ++ct) {
    const int c = ct * 16 + ln15;
    const float bias = b1[e * N1 + c];
#pragma unroll
    for (int r = 0; r < 4; ++r) {
      float v = acc[ct][r] + bias;
      v = v > 0.f ? v : expm1f(v);
      HU[(w * 16 + g * 4 + r) * 136 + c] = f2bf(v);
    }
  }
  __syncthreads();

  // ---------------- Layer 2: [64x128]@[128x96], no barriers ----------------
  f32x4 acc2[6];
#pragma unroll
  for (int j = 0; j < 6; ++j) acc2[j] = (f32x4){0.f, 0.f, 0.f, 0.f};

  const unsigned short* Wt2e =
      Wt2 + (size_t)e * (N2 * N1) + (size_t)ln15 * N1 + g * 8;
  const unsigned short* Hrow = &HU[myrow * 136 + g * 8];
#pragma unroll
  for (int ks = 0; ks < N1 / 32; ++ks) {
    const int k0 = ks * 32;
    bf16x8 a2 = *(const bf16x8*)&Hrow[k0];
#pragma unroll
    for (int ct = 0; ct < 6; ++ct) {
      bf16x8 b2f = *(const bf16x8*)&Wt2e[ct * 16 * N1 + k0];
      acc2[ct] = __builtin_amdgcn_mfma_f32_16x16x32_bf16(a2, b2f, acc2[ct], 0, 0, 0);
    }
  }
  __syncthreads();   // all HU reads done before H2f overlap-write

  // bias + celu (f32), write H2 f32
#pragma unroll
  for (int ct = 0; ct < 6; ++ct) {
    const int c = ct * 16 + ln15;
    const float bias = b2[e * N2 + c];
#pragma unroll
    for (int r = 0; r < 4; ++r) {
      float v = acc2[ct][r] + bias;
      v = v > 0.f ? v : expm1f(v);
      H2f[(w * 16 + g * 4 + r) * 100 + c] = v;
    }
  }
  if (tid < N2 * N3) W3s[tid] = W3[e * N2 * N3 + tid];
  __syncthreads();

  // ---------------- Layer 3: [64x96]@[96x2], fp32 VALU ---------------------
  if (tid < BM * N3) {
    const int m = tid >> 1;
    const int c = tid & 1;
    float s = b3[e * N3 + c];
#pragma unroll
    for (int k4 = 0; k4 < N2; k4 += 4) {
      const float4 h = *(const float4*)&H2f[m * 100 + k4];
      s = fmaf(h.x, W3s[(k4 + 0) * N3 + c], s);
      s = fmaf(h.y, W3s[(k4 + 1) * N3 + c], s);
      s = fmaf(h.z, W3s[(k4 + 2) * N3 + c], s);
      s = fmaf(h.w, W3s[(k4 + 3) * N3 + c], s);
    }
    const int tok = toks[m];
    if (tok >= 0) Y[(size_t)tok * N3 + c] = s;
  }
}

// ---------------------------------------------------------------------------
extern "C" void kernel_launch(void* const* d_in, const int* in_sizes, int n_in,
                              void* d_out, int out_size, void* d_ws, size_t ws_size,
                              hipStream_t stream) {
  const int*   elements = (const int*)d_in[0];
  const float* X  = (const float*)d_in[1];
  const float* W1 = (const float*)d_in[2];
  const float* b1 = (const float*)d_in[3];
  const float* W2 = (const float*)d_in[4];
  const float* b2 = (const float*)d_in[5];
  const float* W3 = (const float*)d_in[6];
  const float* b3 = (const float*)d_in[7];
  const int T = in_sizes[0];        // 131072 tokens

  float* out    = (float*)d_out;
  float* out_el = out;              // output #1: elements (promoted to float)
  float* Y      = out + T;          // output #2: y [T, 2]

  int* ws_i    = (int*)d_ws;
  int* counts  = ws_i;              // [0..4)
  int* cursors = ws_i + 8;          // [8..12)
  int* list    = ws_i + 16;         // T ints

  size_t wt1_off = ((size_t)64 + 4 * (size_t)T + 63) & ~(size_t)63;
  unsigned short* Wt1 = (unsigned short*)((char*)d_ws + wt1_off);
  unsigned short* Wt2 = Wt1 + NEXP * N1 * F_IN;     // +393216 B

  hipMemsetAsync(ws_i, 0, 16 * sizeof(int), stream);
  int nb = (T + 255) / 256;
  hist_kernel<<<nb, 256, 0, stream>>>(elements, out_el, counts, T);
  scan_kernel<<<1, 64, 0, stream>>>(ws_i);
  scatter_kernel<<<nb, 256, 0, stream>>>(elements, cursors, list, T);
  prep_weights<<<(NEXP * N1 * F_IN + NEXP * N2 * N1 + 255) / 256, 256, 0, stream>>>(
      W1, W2, Wt1, Wt2);
  dim3 grid((T + BM - 1) / BM, NEXP);
  moe_mlp_mfma<<<grid, 256, 0, stream>>>(X, b1, b2, W3, b3, ws_i, Wt1, Wt2, Y, T);
}